// Round 1
// baseline (309.687 us; speedup 1.0000x reference)
//
#include <hip/hip_runtime.h>
#include <hip/hip_bf16.h>
#include <stdint.h>

#define LRELU_ALPHA 0.2f
#define EPS_F 1e-8f

constexpr int BB = 8, NN = 2048, FIN = 128, FOUT = 64;

// ---------------- Kernel 1: Wh = h @ W  (fp32, tiled) ----------------
// 256 threads -> 64 rows x 64 cols tile. h tile staged in LDS (padded),
// W read from global (32 KB, L1/L2 resident).
#define HS 132
__global__ __launch_bounds__(256) void k_gemm_hw(const float* __restrict__ h,
                                                 const float* __restrict__ W,
                                                 float* __restrict__ Wh) {
    __shared__ float hs[64 * HS];
    const int tid = threadIdx.x;
    const int base = blockIdx.x * 64;

    // stage h tile (64 rows x 128 k) as float4
    #pragma unroll
    for (int rep = 0; rep < 8; ++rep) {
        int flat4 = rep * 256 + tid;           // 2048 float4 = 8192 floats
        int row = flat4 >> 5, k4 = flat4 & 31;
        float4 v = *reinterpret_cast<const float4*>(h + (size_t)(base + row) * FIN + k4 * 4);
        *reinterpret_cast<float4*>(&hs[row * HS + k4 * 4]) = v;
    }
    __syncthreads();

    const int tr = tid >> 4;   // 0..15 -> 4 rows each
    const int tc = tid & 15;   // 0..15 -> 4 cols each
    float acc[4][4] = {};
    for (int k = 0; k < FIN; ++k) {
        float4 wv = *reinterpret_cast<const float4*>(W + (size_t)k * FOUT + tc * 4);
        #pragma unroll
        for (int r = 0; r < 4; ++r) {
            float hv = hs[(tr * 4 + r) * HS + k];
            acc[r][0] = fmaf(hv, wv.x, acc[r][0]);
            acc[r][1] = fmaf(hv, wv.y, acc[r][1]);
            acc[r][2] = fmaf(hv, wv.z, acc[r][2]);
            acc[r][3] = fmaf(hv, wv.w, acc[r][3]);
        }
    }
    #pragma unroll
    for (int r = 0; r < 4; ++r) {
        float4 o = make_float4(acc[r][0], acc[r][1], acc[r][2], acc[r][3]);
        *reinterpret_cast<float4*>(Wh + (size_t)(base + tr * 4 + r) * FOUT + tc * 4) = o;
    }
}

// ---------------- Kernel 2: s1 = Wh@a1, s2 = Wh@a2, cmax = max(0, max s2) ----
__global__ __launch_bounds__(256) void k_scores(const float* __restrict__ Wh,
                                                const float* __restrict__ a,
                                                float* __restrict__ s1,
                                                float* __restrict__ s2,
                                                int* __restrict__ cmax) {
    const int lane = threadIdx.x & 63;
    const int wid = threadIdx.x >> 6;
    const int row = blockIdx.x * 4 + wid;
    float v = Wh[(size_t)row * FOUT + lane];
    float p1 = v * a[lane];
    float p2 = v * a[FOUT + lane];
    #pragma unroll
    for (int off = 32; off > 0; off >>= 1) {
        p1 += __shfl_xor(p1, off);
        p2 += __shfl_xor(p2, off);
    }
    if (lane == 0) {
        s1[row] = p1;
        s2[row] = p2;
        // positive-float bits are monotone as ints; clamping at 0 is valid
        // (c only needs to be >= row max for stability; result is c-invariant)
        atomicMax(cmax, __float_as_int(fmaxf(p2, 0.0f)));
    }
}

// ---------------- Kernel 3: masked softmax + sparse att@Wh + elu ----------
// One wave per output row. Lane o owns output feature o (FOUT==64).
__global__ __launch_bounds__(256) void k_attn(const float* __restrict__ adj,
                                              const float* __restrict__ Wh,
                                              const float* __restrict__ s1,
                                              const float* __restrict__ s2,
                                              const int* __restrict__ cmax,
                                              float* __restrict__ out) {
    const int lane = threadIdx.x & 63;
    const int wid = threadIdx.x >> 6;
    const int row = blockIdx.x * 4 + wid;      // row = b*N + i
    const int b = row >> 11;                   // N = 2048

    const float M = __int_as_float(*cmax);
    const float s1i = s1[row];
    float cpre = s1i + M;
    const float c = cpre > 0.f ? cpre : LRELU_ALPHA * cpre;   // >= max_j e_ij

    const float* __restrict__ adjrow = adj + (size_t)row * NN;
    const float* __restrict__ WhB = Wh + (size_t)b * NN * FOUT;
    const float* __restrict__ s2B = s2 + (size_t)b * NN;

    float acc = 0.f, S = 0.f, Z = 0.f;

    for (int j0 = 0; j0 < NN; j0 += 64) {
        float av = adjrow[j0 + lane];
        float ev = s1i + s2B[j0 + lane];
        ev = ev > 0.f ? ev : LRELU_ALPHA * ev;
        float ex = __expf(ev - c);
        bool nz = av > 0.f;
        float wv = nz ? av * ex : 0.f;
        S += wv;
        Z += nz ? ex : 0.f;

        uint64_t mask = __ballot(nz);
        const float* __restrict__ basep = WhB + (size_t)j0 * FOUT + lane;
        while (mask) {
            float wq[4], vq[4];
            #pragma unroll
            for (int t = 0; t < 4; ++t) {
                const int src = mask ? (int)__builtin_ctzll(mask) : 0;
                const int wb = __builtin_amdgcn_readlane(__float_as_int(wv), src);
                wq[t] = mask ? __int_as_float(wb) : 0.0f;
                vq[t] = basep[(size_t)src * FOUT];   // dummy (src=0) load when drained
                mask &= mask - 1;
            }
            acc = fmaf(wq[0], vq[0], acc);
            acc = fmaf(wq[1], vq[1], acc);
            acc = fmaf(wq[2], vq[2], acc);
            acc = fmaf(wq[3], vq[3], acc);
        }
    }

    #pragma unroll
    for (int off = 32; off > 0; off >>= 1) {
        S += __shfl_xor(S, off);
        Z += __shfl_xor(Z, off);
    }
    float denom = S + EPS_F * Z;
    float r = acc / denom;
    out[(size_t)row * FOUT + lane] = r > 0.f ? r : expm1f(r);
}

// ---------------------------------------------------------------------------
extern "C" void kernel_launch(void* const* d_in, const int* in_sizes, int n_in,
                              void* d_out, int out_size, void* d_ws, size_t ws_size,
                              hipStream_t stream) {
    (void)in_sizes; (void)n_in; (void)out_size; (void)ws_size;
    const float* h   = (const float*)d_in[0];
    const float* adj = (const float*)d_in[1];
    const float* W   = (const float*)d_in[2];
    const float* a   = (const float*)d_in[3];
    float* out = (float*)d_out;

    float* Wh  = (float*)d_ws;                       // B*N*FOUT floats (4 MB)
    float* s1w = Wh + (size_t)BB * NN * FOUT;        // B*N floats
    float* s2w = s1w + (size_t)BB * NN;              // B*N floats
    int*   cmx = (int*)(s2w + (size_t)BB * NN);      // 1 int

    hipMemsetAsync(cmx, 0, sizeof(int), stream);

    k_gemm_hw<<<(BB * NN) / 64, 256, 0, stream>>>(h, W, Wh);
    k_scores<<<(BB * NN) / 4, 256, 0, stream>>>(Wh, a, s1w, s2w, cmx);
    k_attn<<<(BB * NN) / 4, 256, 0, stream>>>(adj, Wh, s1w, s2w, cmx, out);
}

// Round 2
// 116.400 us; speedup vs baseline: 2.6605x; 2.6605x over previous
//
#include <hip/hip_runtime.h>
#include <hip/hip_bf16.h>
#include <stdint.h>

#define LRELU_ALPHA 0.2f
#define EPS_F 1e-8f

constexpr int BB = 8, NN = 2048, FIN = 128, FOUT = 64;
constexpr int NBLK = BB * NN / 64;   // 256 GEMM blocks -> 256 partial maxes

// ---------------- Kernel 1: Wh = h @ W  (fp32, tiled) + fused s1/s2/pmax ----
// 256 threads -> 64 rows x 64 cols tile; each block owns 64 COMPLETE rows,
// so the row dot-products s1 = Wh@a1, s2 = Wh@a2 are computed here from the
// register accumulators (no extra global pass, no atomics).
#define HS 132
__global__ __launch_bounds__(256) void k_gemm_hw(const float* __restrict__ h,
                                                 const float* __restrict__ W,
                                                 const float* __restrict__ a,
                                                 float* __restrict__ Wh,
                                                 float* __restrict__ s1,
                                                 float* __restrict__ s2,
                                                 float* __restrict__ pmax) {
    __shared__ float hs[64 * HS];
    __shared__ float smax[16];
    const int tid = threadIdx.x;
    const int base = blockIdx.x * 64;

    // stage h tile (64 rows x 128 k) as float4
    #pragma unroll
    for (int rep = 0; rep < 8; ++rep) {
        int flat4 = rep * 256 + tid;           // 2048 float4 = 8192 floats
        int row = flat4 >> 5, k4 = flat4 & 31;
        float4 v = *reinterpret_cast<const float4*>(h + (size_t)(base + row) * FIN + k4 * 4);
        *reinterpret_cast<float4*>(&hs[row * HS + k4 * 4]) = v;
    }
    __syncthreads();

    const int tr = tid >> 4;   // 0..15 -> 4 rows each
    const int tc = tid & 15;   // 0..15 -> 4 cols each
    float acc[4][4] = {};
    for (int k = 0; k < FIN; ++k) {
        float4 wv = *reinterpret_cast<const float4*>(W + (size_t)k * FOUT + tc * 4);
        #pragma unroll
        for (int r = 0; r < 4; ++r) {
            float hv = hs[(tr * 4 + r) * HS + k];
            acc[r][0] = fmaf(hv, wv.x, acc[r][0]);
            acc[r][1] = fmaf(hv, wv.y, acc[r][1]);
            acc[r][2] = fmaf(hv, wv.z, acc[r][2]);
            acc[r][3] = fmaf(hv, wv.w, acc[r][3]);
        }
    }
    #pragma unroll
    for (int r = 0; r < 4; ++r) {
        float4 o = make_float4(acc[r][0], acc[r][1], acc[r][2], acc[r][3]);
        *reinterpret_cast<float4*>(Wh + (size_t)(base + tr * 4 + r) * FOUT + tc * 4) = o;
    }

    // ---- fused s1/s2: reduce acc over the 16-lane tc group ----
    float a1c[4], a2c[4];
    #pragma unroll
    for (int c = 0; c < 4; ++c) {
        a1c[c] = a[tc * 4 + c];
        a2c[c] = a[FOUT + tc * 4 + c];
    }
    float maxp2 = -3.4e38f;
    #pragma unroll
    for (int r = 0; r < 4; ++r) {
        float p1 = acc[r][0] * a1c[0] + acc[r][1] * a1c[1] + acc[r][2] * a1c[2] + acc[r][3] * a1c[3];
        float p2 = acc[r][0] * a2c[0] + acc[r][1] * a2c[1] + acc[r][2] * a2c[2] + acc[r][3] * a2c[3];
        #pragma unroll
        for (int off = 1; off < 16; off <<= 1) {
            p1 += __shfl_xor(p1, off);
            p2 += __shfl_xor(p2, off);
        }
        if (tc == 0) {
            s1[base + tr * 4 + r] = p1;
            s2[base + tr * 4 + r] = p2;
            maxp2 = fmaxf(maxp2, p2);
        }
    }
    if (tc == 0) smax[tr] = maxp2;
    __syncthreads();
    if (tid == 0) {
        float m = smax[0];
        #pragma unroll
        for (int i = 1; i < 16; ++i) m = fmaxf(m, smax[i]);
        pmax[blockIdx.x] = m;   // per-block partial max, NO atomics
    }
}

// ---------------- Kernel 2: masked softmax + sparse att@Wh + elu ----------
// One wave per output row. Lane o owns output feature o (FOUT==64).
__global__ __launch_bounds__(256) void k_attn(const float* __restrict__ adj,
                                              const float* __restrict__ Wh,
                                              const float* __restrict__ s1,
                                              const float* __restrict__ s2,
                                              const float* __restrict__ pmax,
                                              float* __restrict__ out) {
    const int lane = threadIdx.x & 63;
    const int wid = threadIdx.x >> 6;
    const int row = blockIdx.x * 4 + wid;      // row = b*N + i
    const int b = row >> 11;                   // N = 2048

    // reduce the 256 partial maxes (L2-hot) -> global max of s2
    float m = -3.4e38f;
    #pragma unroll
    for (int t = 0; t < 4; ++t) m = fmaxf(m, pmax[lane + t * 64]);
    #pragma unroll
    for (int off = 32; off > 0; off >>= 1) m = fmaxf(m, __shfl_xor(m, off));
    const float M = m;

    const float s1i = s1[row];
    float cpre = s1i + M;
    const float c = cpre > 0.f ? cpre : LRELU_ALPHA * cpre;   // >= max_j e_ij

    const float* __restrict__ adjrow = adj + (size_t)row * NN;
    const float* __restrict__ WhB = Wh + (size_t)b * NN * FOUT;
    const float* __restrict__ s2B = s2 + (size_t)b * NN;

    float acc = 0.f, S = 0.f, Z = 0.f;

    for (int j0 = 0; j0 < NN; j0 += 64) {
        float av = adjrow[j0 + lane];
        float ev = s1i + s2B[j0 + lane];
        ev = ev > 0.f ? ev : LRELU_ALPHA * ev;
        float ex = __expf(ev - c);
        bool nz = av > 0.f;
        float wv = nz ? av * ex : 0.f;
        S += wv;
        Z += nz ? ex : 0.f;

        uint64_t mask = __ballot(nz);
        const float* __restrict__ basep = WhB + (size_t)j0 * FOUT + lane;
        while (mask) {
            float wq[4], vq[4];
            #pragma unroll
            for (int t = 0; t < 4; ++t) {
                const int src = mask ? (int)__builtin_ctzll(mask) : 0;
                const int wb = __builtin_amdgcn_readlane(__float_as_int(wv), src);
                wq[t] = mask ? __int_as_float(wb) : 0.0f;
                vq[t] = basep[(size_t)src * FOUT];   // dummy (src=0) load when drained
                mask &= mask - 1;
            }
            acc = fmaf(wq[0], vq[0], acc);
            acc = fmaf(wq[1], vq[1], acc);
            acc = fmaf(wq[2], vq[2], acc);
            acc = fmaf(wq[3], vq[3], acc);
        }
    }

    #pragma unroll
    for (int off = 32; off > 0; off >>= 1) {
        S += __shfl_xor(S, off);
        Z += __shfl_xor(Z, off);
    }
    float denom = S + EPS_F * Z;
    float r = acc / denom;
    out[(size_t)row * FOUT + lane] = r > 0.f ? r : expm1f(r);
}

// ---------------------------------------------------------------------------
extern "C" void kernel_launch(void* const* d_in, const int* in_sizes, int n_in,
                              void* d_out, int out_size, void* d_ws, size_t ws_size,
                              hipStream_t stream) {
    (void)in_sizes; (void)n_in; (void)out_size; (void)ws_size;
    const float* h   = (const float*)d_in[0];
    const float* adj = (const float*)d_in[1];
    const float* W   = (const float*)d_in[2];
    const float* a   = (const float*)d_in[3];
    float* out = (float*)d_out;

    float* Wh   = (float*)d_ws;                      // B*N*FOUT floats (4 MB)
    float* s1w  = Wh + (size_t)BB * NN * FOUT;       // B*N floats
    float* s2w  = s1w + (size_t)BB * NN;             // B*N floats
    float* pmax = s2w + (size_t)BB * NN;             // NBLK floats

    k_gemm_hw<<<NBLK, 256, 0, stream>>>(h, W, a, Wh, s1w, s2w, pmax);
    k_attn<<<(BB * NN) / 4, 256, 0, stream>>>(adj, Wh, s1w, s2w, pmax, out);
}

// Round 3
// 53.552 us; speedup vs baseline: 5.7830x; 2.1736x over previous
//
#include <hip/hip_runtime.h>
#include <hip/hip_bf16.h>
#include <stdint.h>

#define LRELU_ALPHA 0.2f

constexpr int BB = 8, NN = 2048, FIN = 128, FOUT = 64;

typedef __attribute__((ext_vector_type(8))) short short8;
typedef __attribute__((ext_vector_type(4))) float f32x4;

__device__ __forceinline__ ushort bf16rn(float f) {
    __hip_bfloat16 h = __float2bfloat16(f);
    return *reinterpret_cast<ushort*>(&h);
}

// ---------------- Kernel 1: Wh = h @ W (fp32 regs) -> packed bf16 WhP + s1/s2/pmax
// WhP layout matches the 16x16x32 MFMA B-fragment:
//   WhP[b][jblk(64)][t(4)][lane(64)][e(8)], value = Wh[b][jblk*32 + (lane>>4)*8 + e][t*16 + (lane&15)]
#define HS 132
__global__ __launch_bounds__(256) void k_gemm_hw(const float* __restrict__ h,
                                                 const float* __restrict__ W,
                                                 const float* __restrict__ a,
                                                 ushort* __restrict__ WhP,
                                                 float* __restrict__ s1,
                                                 float* __restrict__ s2,
                                                 float* __restrict__ pmax) {
    __shared__ float hs[64 * HS];
    __shared__ float smax[16];
    const int tid = threadIdx.x;
    const int base = blockIdx.x * 64;

    #pragma unroll
    for (int rep = 0; rep < 8; ++rep) {
        int flat4 = rep * 256 + tid;
        int row = flat4 >> 5, k4 = flat4 & 31;
        float4 v = *reinterpret_cast<const float4*>(h + (size_t)(base + row) * FIN + k4 * 4);
        *reinterpret_cast<float4*>(&hs[row * HS + k4 * 4]) = v;
    }
    __syncthreads();

    const int tr = tid >> 4;   // 4 rows each
    const int tc = tid & 15;   // 4 cols each
    float acc[4][4] = {};
    for (int k = 0; k < FIN; ++k) {
        float4 wv = *reinterpret_cast<const float4*>(W + (size_t)k * FOUT + tc * 4);
        #pragma unroll
        for (int r = 0; r < 4; ++r) {
            float hv = hs[(tr * 4 + r) * HS + k];
            acc[r][0] = fmaf(hv, wv.x, acc[r][0]);
            acc[r][1] = fmaf(hv, wv.y, acc[r][1]);
            acc[r][2] = fmaf(hv, wv.z, acc[r][2]);
            acc[r][3] = fmaf(hv, wv.w, acc[r][3]);
        }
    }

    // ---- packed bf16 stores in B-fragment layout ----
    const int b = base >> 11;
    const int jbase = base & 2047;
    #pragma unroll
    for (int r = 0; r < 4; ++r) {
        const int jloc = jbase + tr * 4 + r;
        const int e = jloc & 7;
        const int kgrp = (jloc >> 3) & 3;
        const int jblk = jloc >> 5;
        #pragma unroll
        for (int c = 0; c < 4; ++c) {
            const int col = tc * 4 + c;
            size_t off = ((((size_t)b * 64 + jblk) * 4 + (col >> 4)) * 64 + kgrp * 16 + (col & 15)) * 8 + e;
            WhP[off] = bf16rn(acc[r][c]);
        }
    }

    // ---- fused s1/s2 row dot-products + per-block max (no atomics) ----
    float a1c[4], a2c[4];
    #pragma unroll
    for (int c = 0; c < 4; ++c) {
        a1c[c] = a[tc * 4 + c];
        a2c[c] = a[FOUT + tc * 4 + c];
    }
    float maxp2 = -3.4e38f;
    #pragma unroll
    for (int r = 0; r < 4; ++r) {
        float p1 = acc[r][0] * a1c[0] + acc[r][1] * a1c[1] + acc[r][2] * a1c[2] + acc[r][3] * a1c[3];
        float p2 = acc[r][0] * a2c[0] + acc[r][1] * a2c[1] + acc[r][2] * a2c[2] + acc[r][3] * a2c[3];
        #pragma unroll
        for (int off = 1; off < 16; off <<= 1) {
            p1 += __shfl_xor(p1, off);
            p2 += __shfl_xor(p2, off);
        }
        if (tc == 0) {
            s1[base + tr * 4 + r] = p1;
            s2[base + tr * 4 + r] = p2;
            maxp2 = fmaxf(maxp2, p2);
        }
    }
    if (tc == 0) smax[tr] = maxp2;
    __syncthreads();
    if (tid == 0) {
        float m = smax[0];
        #pragma unroll
        for (int i = 1; i < 16; ++i) m = fmaxf(m, smax[i]);
        pmax[blockIdx.x] = m;
    }
}

// ---------------- Kernel 2: flash-style masked softmax + MFMA PV ----------
struct Tile {
    float4 a0, a1;     // adj[row][j0 + lk*8 .. +7]
    float4 v0, v1;     // s2 [j0 + lk*8 .. +7]
    short8 b0, b1, b2, b3;  // Wh B-fragments for col tiles 0..3
};

__device__ __forceinline__ void proc8(const Tile& T, float s1i, float c,
                                      float& Sp, short8& af) {
    const float aa[8] = {T.a0.x, T.a0.y, T.a0.z, T.a0.w, T.a1.x, T.a1.y, T.a1.z, T.a1.w};
    const float ss[8] = {T.v0.x, T.v0.y, T.v0.z, T.v0.w, T.v1.x, T.v1.y, T.v1.z, T.v1.w};
    #pragma unroll
    for (int e = 0; e < 8; ++e) {
        float ev = s1i + ss[e];
        ev = ev > 0.f ? ev : LRELU_ALPHA * ev;
        float ex = __expf(ev - c);          // ev <= c  ->  ex in (0,1]
        float wv = aa[e] > 0.f ? aa[e] * ex : 0.f;
        ushort ub = bf16rn(wv);
        Sp += __uint_as_float((uint32_t)ub << 16);   // S from the SAME bf16-rounded P
        af[e] = (short)ub;
    }
}

__global__ __launch_bounds__(256) void k_attn(const float* __restrict__ adj,
                                              const ushort* __restrict__ WhP,
                                              const float* __restrict__ s1,
                                              const float* __restrict__ s2,
                                              const float* __restrict__ pmax,
                                              float* __restrict__ out) {
    const int tid = threadIdx.x;
    const int l = tid & 63, w = tid >> 6;
    const int li = l & 15, lk = l >> 4;
    const int blk = blockIdx.x;
    const int b = blk >> 5;                 // 32 blocks per batch
    const int rowbase = blk * 64 + w * 16;
    const int row_i = rowbase + li;         // this lane's A-fragment row

    // global max of s2 from 256 partials (L2-hot)
    float m = -3.4e38f;
    #pragma unroll
    for (int t = 0; t < 4; ++t) m = fmaxf(m, pmax[l + 64 * t]);
    #pragma unroll
    for (int off = 32; off > 0; off >>= 1) m = fmaxf(m, __shfl_xor(m, off));

    const float s1i = s1[row_i];
    const float cp = s1i + m;
    const float c = cp > 0.f ? cp : LRELU_ALPHA * cp;   // >= max_j e_ij

    const float* __restrict__ adjp = adj + (size_t)row_i * NN + lk * 8;
    const float* __restrict__ s2p  = s2 + (size_t)b * NN + lk * 8;
    const ushort* __restrict__ whp = WhP + (size_t)b * (64 * 4 * 64 * 8) + l * 8;

    f32x4 acc0 = {0.f, 0.f, 0.f, 0.f};
    f32x4 acc1 = {0.f, 0.f, 0.f, 0.f};
    f32x4 acc2 = {0.f, 0.f, 0.f, 0.f};
    f32x4 acc3 = {0.f, 0.f, 0.f, 0.f};
    float Sp = 0.f;

#define LOADT(T, jb) do {                                                     \
        (T).a0 = *reinterpret_cast<const float4*>(adjp + (jb) * 32);          \
        (T).a1 = *reinterpret_cast<const float4*>(adjp + (jb) * 32 + 4);      \
        (T).v0 = *reinterpret_cast<const float4*>(s2p + (jb) * 32);           \
        (T).v1 = *reinterpret_cast<const float4*>(s2p + (jb) * 32 + 4);       \
        const ushort* p_ = whp + (jb) * 2048;                                 \
        (T).b0 = *reinterpret_cast<const short8*>(p_);                        \
        (T).b1 = *reinterpret_cast<const short8*>(p_ + 512);                  \
        (T).b2 = *reinterpret_cast<const short8*>(p_ + 1024);                 \
        (T).b3 = *reinterpret_cast<const short8*>(p_ + 1536);                 \
    } while (0)

#define COMPUTE(T) do {                                                       \
        short8 af;                                                            \
        proc8((T), s1i, c, Sp, af);                                           \
        acc0 = __builtin_amdgcn_mfma_f32_16x16x32_bf16(af, (T).b0, acc0, 0, 0, 0); \
        acc1 = __builtin_amdgcn_mfma_f32_16x16x32_bf16(af, (T).b1, acc1, 0, 0, 0); \
        acc2 = __builtin_amdgcn_mfma_f32_16x16x32_bf16(af, (T).b2, acc2, 0, 0, 0); \
        acc3 = __builtin_amdgcn_mfma_f32_16x16x32_bf16(af, (T).b3, acc3, 0, 0, 0); \
    } while (0)

    Tile t0, t1;
    LOADT(t0, 0);
    LOADT(t1, 1);
    for (int jb = 0; jb < 64; jb += 2) {
        Tile n0, n1;
        if (jb + 2 < 64) {      // depth-2 prefetch: issue before compute
            LOADT(n0, jb + 2);
            LOADT(n1, jb + 3);
        }
        COMPUTE(t0);
        COMPUTE(t1);
        t0 = n0;
        t1 = n1;
    }

    // S: reduce over the 4 k-groups (lanes sharing li), then redistribute to D rows
    float Sred = Sp;
    Sred += __shfl_xor(Sred, 16);
    Sred += __shfl_xor(Sred, 32);   // every lane now has S for row li

    const f32x4 accs[4] = {acc0, acc1, acc2, acc3};
    #pragma unroll
    for (int r = 0; r < 4; ++r) {
        const int drow = lk * 4 + r;    // D-layout row for this lane/reg
        float Sr = __int_as_float(__builtin_amdgcn_ds_bpermute(drow * 4, __float_as_int(Sred)));
        float inv = 1.0f / Sr;
        #pragma unroll
        for (int tt = 0; tt < 4; ++tt) {
            float o = accs[tt][r] * inv;
            o = o > 0.f ? o : expm1f(o);
            out[(size_t)(rowbase + drow) * FOUT + tt * 16 + li] = o;
        }
    }
#undef LOADT
#undef COMPUTE
}

// ---------------------------------------------------------------------------
extern "C" void kernel_launch(void* const* d_in, const int* in_sizes, int n_in,
                              void* d_out, int out_size, void* d_ws, size_t ws_size,
                              hipStream_t stream) {
    (void)in_sizes; (void)n_in; (void)out_size; (void)ws_size;
    const float* h   = (const float*)d_in[0];
    const float* adj = (const float*)d_in[1];
    const float* W   = (const float*)d_in[2];
    const float* a   = (const float*)d_in[3];
    float* out = (float*)d_out;

    ushort* WhP = (ushort*)d_ws;                          // B*N*F bf16 = 2 MB
    float* s1w  = (float*)(WhP + (size_t)BB * NN * FOUT);
    float* s2w  = s1w + (size_t)BB * NN;
    float* pmaxw = s2w + (size_t)BB * NN;

    k_gemm_hw<<<BB * NN / 64, 256, 0, stream>>>(h, W, a, WhP, s1w, s2w, pmaxw);
    k_attn<<<BB * NN / 64, 256, 0, stream>>>(adj, WhP, s1w, s2w, pmaxw, out);
}

// Round 4
// 52.192 us; speedup vs baseline: 5.9336x; 1.0260x over previous
//
#include <hip/hip_runtime.h>
#include <hip/hip_bf16.h>
#include <stdint.h>

#define LRELU_ALPHA 0.2f
#define L2E 1.44269504f

constexpr int BB = 8, NN = 2048, FIN = 128, FOUT = 64;
constexpr int GEMM_ROWS = 32;
constexpr int NBLK_G = BB * NN / GEMM_ROWS;   // 512 partial maxes

typedef __attribute__((ext_vector_type(8))) short short8;
typedef __attribute__((ext_vector_type(4))) float f32x4;

__device__ __forceinline__ ushort bf16rn(float f) {
    __hip_bfloat16 h = __float2bfloat16(f);
    return *reinterpret_cast<ushort*>(&h);
}

// ---------------- Kernel 1: Wh = h @ W (fp32) -> packed bf16 WhP + s1/s2/pmax
// 32-row tiles, 512 blocks (2 blocks/CU). Each thread: 2 rows x 4 cols.
// WhP layout = 16x16x32 MFMA B-fragment:
//   WhP[b][jblk(64)][t(4)][lane(64)][e(8)] = Wh[b][jblk*32 + (lane>>4)*8 + e][t*16 + (lane&15)]
#define HS 132
__global__ __launch_bounds__(256) void k_gemm_hw(const float* __restrict__ h,
                                                 const float* __restrict__ W,
                                                 const float* __restrict__ a,
                                                 ushort* __restrict__ WhP,
                                                 float* __restrict__ s1,
                                                 float* __restrict__ s2,
                                                 float* __restrict__ pmax) {
    __shared__ float hs[GEMM_ROWS * HS];
    __shared__ float smax[16];
    const int tid = threadIdx.x;
    const int base = blockIdx.x * GEMM_ROWS;

    // stage h tile (32 rows x 128 k) as float4: 1024 float4, 4 reps
    #pragma unroll
    for (int rep = 0; rep < 4; ++rep) {
        int flat4 = rep * 256 + tid;
        int row = flat4 >> 5, k4 = flat4 & 31;
        float4 v = *reinterpret_cast<const float4*>(h + (size_t)(base + row) * FIN + k4 * 4);
        *reinterpret_cast<float4*>(&hs[row * HS + k4 * 4]) = v;
    }
    __syncthreads();

    const int tr = tid >> 4;   // 0..15 -> 2 rows each
    const int tc = tid & 15;   // 0..15 -> 4 cols each
    float acc[2][4] = {};
    #pragma unroll 4
    for (int k = 0; k < FIN; ++k) {
        float4 wv = *reinterpret_cast<const float4*>(W + (size_t)k * FOUT + tc * 4);
        #pragma unroll
        for (int r = 0; r < 2; ++r) {
            float hv = hs[(tr * 2 + r) * HS + k];
            acc[r][0] = fmaf(hv, wv.x, acc[r][0]);
            acc[r][1] = fmaf(hv, wv.y, acc[r][1]);
            acc[r][2] = fmaf(hv, wv.z, acc[r][2]);
            acc[r][3] = fmaf(hv, wv.w, acc[r][3]);
        }
    }

    // ---- packed bf16 stores in B-fragment layout ----
    const int b = base >> 11;
    const int jbase = base & 2047;
    #pragma unroll
    for (int r = 0; r < 2; ++r) {
        const int jloc = jbase + tr * 2 + r;
        const int e = jloc & 7;
        const int kgrp = (jloc >> 3) & 3;
        const int jblk = jloc >> 5;
        #pragma unroll
        for (int c = 0; c < 4; ++c) {
            const int col = tc * 4 + c;
            size_t off = ((((size_t)b * 64 + jblk) * 4 + (col >> 4)) * 64 + kgrp * 16 + (col & 15)) * 8 + e;
            WhP[off] = bf16rn(acc[r][c]);
        }
    }

    // ---- fused s1/s2 row dot-products + per-block max (no atomics) ----
    float a1c[4], a2c[4];
    #pragma unroll
    for (int c = 0; c < 4; ++c) {
        a1c[c] = a[tc * 4 + c];
        a2c[c] = a[FOUT + tc * 4 + c];
    }
    float maxp2 = -3.4e38f;
    #pragma unroll
    for (int r = 0; r < 2; ++r) {
        float p1 = acc[r][0] * a1c[0] + acc[r][1] * a1c[1] + acc[r][2] * a1c[2] + acc[r][3] * a1c[3];
        float p2 = acc[r][0] * a2c[0] + acc[r][1] * a2c[1] + acc[r][2] * a2c[2] + acc[r][3] * a2c[3];
        #pragma unroll
        for (int off = 1; off < 16; off <<= 1) {
            p1 += __shfl_xor(p1, off);
            p2 += __shfl_xor(p2, off);
        }
        if (tc == 0) {
            s1[base + tr * 2 + r] = p1;
            s2[base + tr * 2 + r] = p2;
            maxp2 = fmaxf(maxp2, p2);
        }
    }
    if (tc == 0) smax[tr] = maxp2;
    __syncthreads();
    if (tid == 0) {
        float m = smax[0];
        #pragma unroll
        for (int i = 1; i < 16; ++i) m = fmaxf(m, smax[i]);
        pmax[blockIdx.x] = m;
    }
}

// ---------------- Kernel 2: flash-style masked softmax + MFMA PV ----------
// 16 rows per block, 4 waves each owning a 512-wide j-slice (16 tiles of 32).
// 4 waves/SIMD occupancy; LDS cross-wave reduction of partial acc/S.
__global__ __launch_bounds__(256, 4) void k_attn(const float* __restrict__ adj,
                                                 const ushort* __restrict__ WhP,
                                                 const float* __restrict__ s1,
                                                 const float* __restrict__ s2,
                                                 const float* __restrict__ pmax,
                                                 float* __restrict__ out) {
    __shared__ float lacc[4][16][68];   // +4 pad -> write conflict-free
    __shared__ float lS[4][16];

    const int tid = threadIdx.x;
    const int l = tid & 63, w = tid >> 6;
    const int li = l & 15, lk = l >> 4;
    const int blk = blockIdx.x;
    const int b = blk >> 7;             // 128 blocks per batch
    const int rowbase = blk * 16;       // global row (= b*N + i base)
    const int row_i = rowbase + li;

    // global max of s2 from 512 partials (L2-hot)
    float m = -3.4e38f;
    #pragma unroll
    for (int t = 0; t < 8; ++t) m = fmaxf(m, pmax[l + 64 * t]);
    #pragma unroll
    for (int off = 32; off > 0; off >>= 1) m = fmaxf(m, __shfl_xor(m, off));

    const float s1i = s1[row_i];
    const float cp = s1i + m;
    const float c = fmaxf(cp, LRELU_ALPHA * cp);   // lrelu(cp) >= max_j e_ij
    const float cL = c * L2E;

    const float* __restrict__ adjp = adj + (size_t)row_i * NN + w * 512 + lk * 8;
    const float* __restrict__ s2p  = s2 + (size_t)b * NN + w * 512 + lk * 8;
    const ushort* __restrict__ whp = WhP + (size_t)b * 131072 + (size_t)(w * 16) * 2048 + l * 8;

    f32x4 acc0 = {0.f, 0.f, 0.f, 0.f};
    f32x4 acc1 = {0.f, 0.f, 0.f, 0.f};
    f32x4 acc2 = {0.f, 0.f, 0.f, 0.f};
    f32x4 acc3 = {0.f, 0.f, 0.f, 0.f};
    float Sp = 0.f;

    // adj double-buffer prefetch (static indices via full unroll)
    float4 pa[2][2];
    pa[0][0] = *reinterpret_cast<const float4*>(adjp);
    pa[0][1] = *reinterpret_cast<const float4*>(adjp + 4);
    pa[1][0] = *reinterpret_cast<const float4*>(adjp + 32);
    pa[1][1] = *reinterpret_cast<const float4*>(adjp + 36);

    #pragma unroll
    for (int t = 0; t < 16; ++t) {
        const float4 a0 = pa[t & 1][0];
        const float4 a1 = pa[t & 1][1];
        if (t + 2 < 16) {
            pa[t & 1][0] = *reinterpret_cast<const float4*>(adjp + (t + 2) * 32);
            pa[t & 1][1] = *reinterpret_cast<const float4*>(adjp + (t + 2) * 32 + 4);
        }
        const float4 v0 = *reinterpret_cast<const float4*>(s2p + t * 32);
        const float4 v1 = *reinterpret_cast<const float4*>(s2p + t * 32 + 4);
        const ushort* p_ = whp + t * 2048;
        const short8 b0 = *reinterpret_cast<const short8*>(p_);
        const short8 b1 = *reinterpret_cast<const short8*>(p_ + 512);
        const short8 b2 = *reinterpret_cast<const short8*>(p_ + 1024);
        const short8 b3 = *reinterpret_cast<const short8*>(p_ + 1536);

        const float aa[8] = {a0.x, a0.y, a0.z, a0.w, a1.x, a1.y, a1.z, a1.w};
        const float ss[8] = {v0.x, v0.y, v0.z, v0.w, v1.x, v1.y, v1.z, v1.w};
        short8 af;
        #pragma unroll
        for (int e = 0; e < 8; ++e) {
            float ev = s1i + ss[e];
            float lr = fmaxf(ev, LRELU_ALPHA * ev);          // leaky_relu
            float ex = exp2f(fmaf(lr, L2E, -cL));            // exp(lr - c), <= 1
            float wv = aa[e] * ex;                           // adj >= 0 -> no select
            ushort ub = bf16rn(wv);
            Sp += __uint_as_float((uint32_t)ub << 16);       // S from SAME rounded P
            af[e] = (short)ub;
        }
        acc0 = __builtin_amdgcn_mfma_f32_16x16x32_bf16(af, b0, acc0, 0, 0, 0);
        acc1 = __builtin_amdgcn_mfma_f32_16x16x32_bf16(af, b1, acc1, 0, 0, 0);
        acc2 = __builtin_amdgcn_mfma_f32_16x16x32_bf16(af, b2, acc2, 0, 0, 0);
        acc3 = __builtin_amdgcn_mfma_f32_16x16x32_bf16(af, b3, acc3, 0, 0, 0);
    }

    // partial S for row li of this wave's j-slice
    float Sred = Sp;
    Sred += __shfl_xor(Sred, 16);
    Sred += __shfl_xor(Sred, 32);
    if (l < 16) lS[w][li] = Sred;

    // partial acc -> LDS in D layout (row = lk*4+r, col = tt*16+li)
    const f32x4 accs[4] = {acc0, acc1, acc2, acc3};
    #pragma unroll
    for (int r = 0; r < 4; ++r)
        #pragma unroll
        for (int tt = 0; tt < 4; ++tt)
            lacc[w][lk * 4 + r][tt * 16 + li] = accs[tt][r];

    __syncthreads();

    // combine: 1024 outputs, 4 per thread
    #pragma unroll
    for (int q = 0; q < 4; ++q) {
        const int idx = q * 256 + tid;
        const int row = idx >> 6, col = idx & 63;
        float v = lacc[0][row][col] + lacc[1][row][col] + lacc[2][row][col] + lacc[3][row][col];
        float S = lS[0][row] + lS[1][row] + lS[2][row] + lS[3][row];
        float o = v / S;
        o = o > 0.f ? o : expm1f(o);
        out[(size_t)(rowbase + row) * FOUT + col] = o;
    }
}

// ---------------------------------------------------------------------------
extern "C" void kernel_launch(void* const* d_in, const int* in_sizes, int n_in,
                              void* d_out, int out_size, void* d_ws, size_t ws_size,
                              hipStream_t stream) {
    (void)in_sizes; (void)n_in; (void)out_size; (void)ws_size;
    const float* h   = (const float*)d_in[0];
    const float* adj = (const float*)d_in[1];
    const float* W   = (const float*)d_in[2];
    const float* a   = (const float*)d_in[3];
    float* out = (float*)d_out;

    ushort* WhP = (ushort*)d_ws;                          // B*N*F bf16 = 2 MB
    float* s1w  = (float*)(WhP + (size_t)BB * NN * FOUT);
    float* s2w  = s1w + (size_t)BB * NN;
    float* pmaxw = s2w + (size_t)BB * NN;                 // NBLK_G floats

    k_gemm_hw<<<NBLK_G, 256, 0, stream>>>(h, W, a, WhP, s1w, s2w, pmaxw);
    k_attn<<<BB * NN / 16, 256, 0, stream>>>(adj, WhP, s1w, s2w, pmaxw, out);
}